// Round 15
// baseline (148.288 us; speedup 1.0000x reference)
//
#include <hip/hip_runtime.h>
#include <hip/hip_fp16.h>
#include <cstdint>
#include <cstddef>

#define NN 100000
#define NE 1200000
#define NBKT 1563              // (NN+63)/64 buckets of 64 dst nodes
#define CAP_B 1536             // slab capacity per bucket (mean 768, +27 sigma)
#define PBLK 256               // partition blocks (1 per CU)
#define PCHK ((NE + PBLK - 1) / PBLK)   // 4688 edges per partition block
#define SSTR2 (NBKT * 64 * 4)  // uint2 elems per 16-feature strip (400128)
#define SSTRH (NBKT * 64 * 16) // fp16 elems per strip (1600512)

typedef _Float16 f16x8 __attribute__((ext_vector_type(8)));
typedef float f32x4 __attribute__((ext_vector_type(4)));

// ================= init: zero cursors + overflow count in ONE dispatch =================
__global__ void zero_kernel(int* __restrict__ cur, unsigned* __restrict__ ovfn) {
    int i = blockIdx.x * blockDim.x + threadIdx.x;
    if (i < NBKT) cur[i] = 0;
    if (i == NBKT) *ovfn = 0;
}

// ============ partition: hierarchical reservation; 1024 thr = 4 waves/SIMD TLP ============
__global__ __launch_bounds__(1024) void partition_hier(
    const int* __restrict__ ei, int* __restrict__ cur,
    unsigned* __restrict__ recs, unsigned* __restrict__ ovfn,
    uint2* __restrict__ ovf, int E) {
    __shared__ int hist[NBKT];
    __shared__ int base[NBKT];
    const int tid = threadIdx.x;
    for (int i = tid; i < NBKT; i += 1024) hist[i] = 0;
    __syncthreads();
    const int lo = blockIdx.x * PCHK, hi = min(lo + PCHK, E);
    for (int e = lo + tid; e < hi; e += 1024)
        atomicAdd(&hist[ei[E + e] >> 6], 1);
    __syncthreads();
    for (int i = tid; i < NBKT; i += 1024) {
        int c = hist[i];
        base[i] = c ? atomicAdd(&cur[i], c) : 0;
        hist[i] = 0;   // reuse as local cursor
    }
    __syncthreads();
    for (int e = lo + tid; e < hi; e += 1024) {
        int d = ei[E + e];
        int s = ei[e];
        int b = d >> 6;
        int lp = atomicAdd(&hist[b], 1);
        int pos = base[b] + lp;
        if (pos < CAP_B)
            recs[(size_t)b * CAP_B + pos] = ((unsigned)s << 6) | (unsigned)(d & 63);
        else {   // ~27 sigma out; keep exact anyway
            unsigned o = atomicAdd(ovfn, 1);
            if (o < 4096) ovf[o] = make_uint2((unsigned)s, (unsigned)d);
        }
    }
}

// ============ one-time per-bucket counting sort + per-node offsets + dis ============
__global__ __launch_bounds__(256) void sort_bucket(
    const int* __restrict__ cur, unsigned* __restrict__ recs,
    const unsigned* __restrict__ ovfn, const uint2* __restrict__ ovf,
    float* __restrict__ dis, int* __restrict__ offn, int n) {
    __shared__ unsigned raw[CAP_B], srt[CAP_B];
    __shared__ int cnt[64], pfx[64], woff[64];
    const int b = blockIdx.x, tid = threadIdx.x;
    if (tid < 64) cnt[tid] = 0;
    const int c = min(cur[b], CAP_B);
    unsigned* slab = recs + (size_t)b * CAP_B;
    for (int i = tid; i < c; i += 256) raw[i] = slab[i];
    __syncthreads();
    for (int i = tid; i < c; i += 256) atomicAdd(&cnt[raw[i] & 63], 1);
    __syncthreads();
    if (tid < 64) pfx[tid] = cnt[tid];
    __syncthreads();
    for (int s = 1; s < 64; s <<= 1) {
        int v = (tid < 64 && tid >= s) ? pfx[tid - s] : 0;
        __syncthreads();
        if (tid < 64) pfx[tid] += v;
        __syncthreads();
    }
    if (tid < 64) woff[tid] = pfx[tid] - cnt[tid];
    __syncthreads();
    for (int i = tid; i < c; i += 256) {
        unsigned k = raw[i];
        int p = atomicAdd(&woff[k & 63], 1);
        srt[p] = k >> 6;          // plain src id, sorted by dst-low
    }
    __syncthreads();
    for (int i = tid; i < c; i += 256) slab[i] = srt[i];
    if (tid < 64) {
        int g = b * 64 + tid;
        if (g < n) {
            int cc = cnt[tid];
            unsigned no = *ovfn;
            for (unsigned i = 0; i < no; i++)
                if ((int)ovf[i].y == g) cc++;
            dis[g] = rsqrtf((float)cc + 1.0f);   // +1 self-loop
            offn[g] = pfx[tid] - cnt[tid];
        }
    }
}

#define LD1(q) { float2 g01 = __half22float2(*(__half2*)&(q).x); \
                 float2 g23 = __half22float2(*(__half2*)&(q).y); \
                 a0 += g01.x; a1 += g01.y; a2 += g23.x; a3 += g23.y; }

// ============ strip aggregation: XCD-local L2 gathers ============
// Grid NBKT*8; bid&7 = XCD lane (round-robin dispatch): strip q = bid&3 (16 feats,
// 3.2MB strip-major region -> fits 4MiB per-XCD L2), half h = (bid>>2)&1 (32 nodes).
// 128 thr: one 4-lane subgroup per node, 8-deep batched 8B gathers.
// hw rows already carry dis[src]; output applies dis[dst], bias, relu.
template <bool HALF_OUT>
__global__ __launch_bounds__(128) void agg_strip(
    const int* __restrict__ cur, const unsigned* __restrict__ recs,
    const int* __restrict__ offn, const __half* __restrict__ hw,
    const float* __restrict__ dis, const float* __restrict__ bias,
    void* __restrict__ outv,
    const unsigned* __restrict__ ovfn, const uint2* __restrict__ ovf, int n) {
    __shared__ int soff[33];
    __shared__ float sdis[32];
    const int bid = blockIdx.x, tid = threadIdx.x;
    const int b = bid >> 3;
    const int q = bid & 3;          // feature strip
    const int h = (bid >> 2) & 1;   // node half
    const int c = min(cur[b], CAP_B);

    if (tid < 33) {
        int g2 = b * 64 + h * 32 + tid;
        soff[tid] = ((h == 1 && tid == 32) || g2 >= n) ? c : offn[g2];
    }
    if (tid < 32) {
        int g2 = b * 64 + h * 32 + tid;
        sdis[tid] = (g2 < n) ? dis[g2] : 0.f;
    }
    __syncthreads();

    const int nl = tid >> 2;        // node 0..31 within half
    const int sub = tid & 3;        // feature quad within strip
    const int g = b * 64 + h * 32 + nl;
    if (g >= n) return;

    const uint2* hq = (const uint2*)hw + (size_t)q * SSTR2;
    const unsigned* slab = recs + (size_t)b * CAP_B;

    uint2 qs = hq[(size_t)g * 4 + sub];   // self row (carries dis[g])
    float a0 = 0.f, a1 = 0.f, a2 = 0.f, a3 = 0.f;
    LD1(qs);

    int e = soff[nl], end = soff[nl + 1];
    for (; e + 8 <= end; e += 8) {
        unsigned s0 = slab[e + 0], s1 = slab[e + 1], s2 = slab[e + 2], s3 = slab[e + 3];
        unsigned s4 = slab[e + 4], s5 = slab[e + 5], s6 = slab[e + 6], s7 = slab[e + 7];
        uint2 q0 = hq[(size_t)s0 * 4 + sub];
        uint2 q1 = hq[(size_t)s1 * 4 + sub];
        uint2 q2 = hq[(size_t)s2 * 4 + sub];
        uint2 q3 = hq[(size_t)s3 * 4 + sub];
        uint2 q4 = hq[(size_t)s4 * 4 + sub];
        uint2 q5 = hq[(size_t)s5 * 4 + sub];
        uint2 q6 = hq[(size_t)s6 * 4 + sub];
        uint2 q7 = hq[(size_t)s7 * 4 + sub];
        LD1(q0); LD1(q1); LD1(q2); LD1(q3);
        LD1(q4); LD1(q5); LD1(q6); LD1(q7);
    }
    for (; e < end; e++) {
        uint2 qq = hq[(size_t)slab[e] * 4 + sub];
        LD1(qq);
    }
    unsigned no = *ovfn;
    for (unsigned i = 0; i < no; i++) {
        uint2 o = ovf[i];
        if ((int)o.y == g) { uint2 qq = hq[(size_t)o.x * 4 + sub]; LD1(qq); }
    }

    float di = sdis[nl];
    const float4 bb = ((const float4*)bias)[q * 4 + sub];
    float o0 = fmaf(di, a0, bb.x);
    float o1 = fmaf(di, a1, bb.y);
    float o2 = fmaf(di, a2, bb.z);
    float o3 = fmaf(di, a3, bb.w);
    o0 = o0 > 0.f ? o0 : 0.f;
    o1 = o1 > 0.f ? o1 : 0.f;
    o2 = o2 > 0.f ? o2 : 0.f;
    o3 = o3 > 0.f ? o3 : 0.f;
    if (HALF_OUT) {
        __half2 p01 = __floats2half2_rn(o0, o1);
        __half2 p23 = __floats2half2_rn(o2, o3);
        uint2 pk;
        pk.x = *(unsigned*)&p01;
        pk.y = *(unsigned*)&p23;
        ((uint2*)outv)[(size_t)q * SSTR2 + (size_t)g * 4 + sub] = pk;
    } else {
        float4 oo; oo.x = o0; oo.y = o1; oo.z = o2; oo.w = o3;
        ((float4*)outv)[(size_t)g * 16 + q * 4 + sub] = oo;
    }
}

// ============ MFMA GEMM (fp32 in): C = (A @ W) * dis[row], fp16 STRIP-major out ============
template <int K>
__global__ __launch_bounds__(256) void gemm_mfma(const float* __restrict__ A,
                                                 const float* __restrict__ W,
                                                 const float* __restrict__ dis,
                                                 __half* __restrict__ C, int n) {
    constexpr int KB = K / 32;
    __shared__ f16x8 sAf[4 * KB * 64];   // [rt][kb][lane]
    __shared__ f16x8 sWf[4 * KB * 64];   // [ct][kb][lane]
    __shared__ float sdis[64];
    const int tid = threadIdx.x;
    const int row0 = blockIdx.x * 64;

    if (tid < 64) {
        int rw = row0 + tid;
        sdis[tid] = (rw < n) ? dis[rw] : 0.f;
    }

    _Float16* sAh = (_Float16*)sAf;
    const float4* A4 = (const float4*)A;
#pragma unroll
    for (int it = 0; it < K / 16; ++it) {
        int f = it * 256 + tid;
        int row = f / (K / 4);
        int kq = f % (K / 4);
        int k0 = kq * 4;
        float4 a;
        if (row0 + row < n) a = A4[(size_t)(row0 + row) * (K / 4) + kq];
        else { a.x = 0.f; a.y = 0.f; a.z = 0.f; a.w = 0.f; }
        int rt = row >> 4;
        int kb = k0 >> 5;
        int lane = (row & 15) | (((k0 >> 3) & 3) << 4);
        int base = ((rt * KB + kb) * 64 + lane) * 8 + (k0 & 7);
        sAh[base + 0] = (_Float16)a.x;
        sAh[base + 1] = (_Float16)a.y;
        sAh[base + 2] = (_Float16)a.z;
        sAh[base + 3] = (_Float16)a.w;
    }
    _Float16* sWh = (_Float16*)sWf;
    {
        int nn = tid & 63;
        int ct = nn >> 4;
        int lbase = nn & 15;
        for (int k = tid >> 6; k < K; k += 4) {
            float w = W[(size_t)k * 64 + nn];
            int kb = k >> 5;
            int lane = lbase | (((k >> 3) & 3) << 4);
            sWh[((ct * KB + kb) * 64 + lane) * 8 + (k & 7)] = (_Float16)w;
        }
    }
    __syncthreads();

    const int wv = tid >> 6;     // wave id = col-tile = STRIP id
    const int lane = tid & 63;
    f32x4 acc[4];
#pragma unroll
    for (int rt = 0; rt < 4; ++rt) acc[rt] = (f32x4){0.f, 0.f, 0.f, 0.f};

#pragma unroll
    for (int kb = 0; kb < KB; ++kb) {
        f16x8 bf = sWf[(wv * KB + kb) * 64 + lane];
#pragma unroll
        for (int rt = 0; rt < 4; ++rt) {
            f16x8 af = sAf[(rt * KB + kb) * 64 + lane];
            acc[rt] = __builtin_amdgcn_mfma_f32_16x16x32_f16(af, bf, acc[rt], 0, 0, 0);
        }
    }

    int col16 = lane & 15;
    int rbase = (lane >> 4) * 4;
#pragma unroll
    for (int rt = 0; rt < 4; ++rt) {
#pragma unroll
        for (int r = 0; r < 4; ++r) {
            int row = row0 + rt * 16 + rbase + r;
            if (row < n)
                C[(size_t)wv * SSTRH + (size_t)row * 16 + col16] =
                    __float2half(acc[rt][r] * sdis[rt * 16 + rbase + r]);
        }
    }
}

// ====== MFMA GEMM (fp16 STRIP-major in, K=64): C = (A @ W) * dis[row], strip out ======
__global__ __launch_bounds__(256) void gemm_mfma_h(const __half* __restrict__ A,
                                                   const float* __restrict__ W,
                                                   const float* __restrict__ dis,
                                                   __half* __restrict__ C, int n) {
    constexpr int K = 64, KB = 2;
    __shared__ f16x8 sAf[4 * KB * 64];
    __shared__ f16x8 sWf[4 * KB * 64];
    __shared__ float sdis[64];
    const int tid = threadIdx.x;
    const int row0 = blockIdx.x * 64;

    if (tid < 64) {
        int rw = row0 + tid;
        sdis[tid] = (rw < n) ? dis[rw] : 0.f;
    }

    _Float16* sAh = (_Float16*)sAf;
    const uint2* A2 = (const uint2*)A;   // strip-major: strip q holds rows of 4 uint2
#pragma unroll
    for (int it = 0; it < 4; ++it) {     // 64 rows * 16 = 1024 uint2 / 256 thr
        int f = it * 256 + tid;
        int row = f >> 4;
        int kq = f & 15;
        int k0 = kq * 4;
        int q = kq >> 2;                 // source strip
        uint2 a;
        if (row0 + row < n) a = A2[(size_t)q * SSTR2 + (size_t)(row0 + row) * 4 + (kq & 3)];
        else { a.x = 0u; a.y = 0u; }
        _Float16* ap = (_Float16*)&a;
        int rt = row >> 4;
        int kb = k0 >> 5;
        int lane = (row & 15) | (((k0 >> 3) & 3) << 4);
        int base = ((rt * KB + kb) * 64 + lane) * 8 + (k0 & 7);
        sAh[base + 0] = ap[0];
        sAh[base + 1] = ap[1];
        sAh[base + 2] = ap[2];
        sAh[base + 3] = ap[3];
    }
    _Float16* sWh = (_Float16*)sWf;
    {
        int nn = tid & 63;
        int ct = nn >> 4;
        int lbase = nn & 15;
        for (int k = tid >> 6; k < K; k += 4) {
            float w = W[(size_t)k * 64 + nn];
            int kb = k >> 5;
            int lane = lbase | (((k >> 3) & 3) << 4);
            sWh[((ct * KB + kb) * 64 + lane) * 8 + (k & 7)] = (_Float16)w;
        }
    }
    __syncthreads();

    const int wv = tid >> 6;
    const int lane = tid & 63;
    f32x4 acc[4];
#pragma unroll
    for (int rt = 0; rt < 4; ++rt) acc[rt] = (f32x4){0.f, 0.f, 0.f, 0.f};

#pragma unroll
    for (int kb = 0; kb < KB; ++kb) {
        f16x8 bf = sWf[(wv * KB + kb) * 64 + lane];
#pragma unroll
        for (int rt = 0; rt < 4; ++rt) {
            f16x8 af = sAf[(rt * KB + kb) * 64 + lane];
            acc[rt] = __builtin_amdgcn_mfma_f32_16x16x32_f16(af, bf, acc[rt], 0, 0, 0);
        }
    }

    int col16 = lane & 15;
    int rbase = (lane >> 4) * 4;
#pragma unroll
    for (int rt = 0; rt < 4; ++rt) {
#pragma unroll
        for (int r = 0; r < 4; ++r) {
            int row = row0 + rt * 16 + rbase + r;
            if (row < n)
                C[(size_t)wv * SSTRH + (size_t)row * 16 + col16] =
                    __float2half(acc[rt][r] * sdis[rt * 16 + rbase + r]);
        }
    }
}

// ================= fallback (atomic path, small ws) =================
__global__ void fill_kernel(float* __restrict__ p, float v, int n) {
    int i = blockIdx.x * blockDim.x + threadIdx.x;
    if (i < n) p[i] = v;
}
__global__ void degree_kernel(const int* __restrict__ ei, float* __restrict__ deg, int E) {
    int stride = gridDim.x * blockDim.x;
    for (int e = blockIdx.x * blockDim.x + threadIdx.x; e < E; e += stride)
        atomicAdd(&deg[ei[E + e]], 1.0f);
}
__global__ void rsqrt_kernel(float* __restrict__ deg, int n) {
    int i = blockIdx.x * blockDim.x + threadIdx.x;
    if (i < n) deg[i] = rsqrtf(deg[i]);
}
template <int K>
__global__ __launch_bounds__(256) void gemm_tile(const float* __restrict__ A,
                                                 const float* __restrict__ W,
                                                 float* __restrict__ C, int n) {
    __shared__ float sA[64 * K];
    __shared__ float sW[K * 64];
    const int tid = threadIdx.x;
    const int row0 = blockIdx.x * 64;
    const int rows = min(64, n - row0);
    const float4* W4 = (const float4*)W;
    float4* sW4 = (float4*)sW;
    for (int i = tid; i < K * 16; i += 256) sW4[i] = W4[i];
    const float4* A4 = (const float4*)(A + (size_t)row0 * K);
    float4* sA4 = (float4*)sA;
    const int nElem = rows * (K / 4);
    for (int i = tid; i < nElem; i += 256) sA4[i] = A4[i];
    __syncthreads();
    const int col = tid & 63;
    const int ty  = tid >> 6;
    float acc[16];
#pragma unroll
    for (int r = 0; r < 16; r++) acc[r] = 0.f;
    for (int k = 0; k < K; k += 4) {
        float w0 = sW[(k + 0) * 64 + col];
        float w1 = sW[(k + 1) * 64 + col];
        float w2 = sW[(k + 2) * 64 + col];
        float w3 = sW[(k + 3) * 64 + col];
#pragma unroll
        for (int r = 0; r < 16; r++) {
            const float4 a = *(const float4*)&sA[(ty + 4 * r) * K + k];
            acc[r] = fmaf(a.x, w0, acc[r]);
            acc[r] = fmaf(a.y, w1, acc[r]);
            acc[r] = fmaf(a.z, w2, acc[r]);
            acc[r] = fmaf(a.w, w3, acc[r]);
        }
    }
#pragma unroll
    for (int r = 0; r < 16; r++) {
        int row = ty + 4 * r;
        if (row < rows) C[(size_t)(row0 + row) * 64 + col] = acc[r];
    }
}
__global__ void scatter_kernel(const int* __restrict__ ei, const float* __restrict__ hw,
                               const float* __restrict__ dis, float* __restrict__ agg, int E) {
    int gtid = blockIdx.x * blockDim.x + threadIdx.x;
    int wave = gtid >> 6, lane = threadIdx.x & 63;
    int nwaves = (gridDim.x * blockDim.x) >> 6;
    for (int e = wave; e < E; e += nwaves) {
        int s = ei[e], d = ei[E + e];
        float v = hw[(size_t)s * 64 + lane] * dis[s] * dis[d];
        atomicAdd(&agg[(size_t)d * 64 + lane], v);
    }
}
__global__ void finalize_kernel(float* __restrict__ agg, const float* __restrict__ hw,
                                const float* __restrict__ dis, const float* __restrict__ b, int n) {
    int i = blockIdx.x * blockDim.x + threadIdx.x;
    if (i < n * 64) {
        int node = i >> 6, col = i & 63;
        float di = dis[node];
        float v = agg[i] + hw[i] * di * di + b[col];
        agg[i] = v > 0.0f ? v : 0.0f;
    }
}

extern "C" void kernel_launch(void* const* d_in, const int* in_sizes, int n_in,
                              void* d_out, int out_size, void* d_ws, size_t ws_size,
                              hipStream_t stream) {
    const float* x  = (const float*)d_in[0];
    const int*   ei = (const int*)d_in[1];   // int32 [2, E] flat
    const float* W1 = (const float*)d_in[2];
    const float* b1 = (const float*)d_in[3];
    const float* W2 = (const float*)d_in[4];
    const float* b2 = (const float*)d_in[5];
    float* out = (float*)d_out;

    const int N = NN, E = NE;
    char* ws = (char*)d_ws;
    const int gemmGrid = (N + 63) / 64;

    if (ws_size >= 38200000u) {
        // ---- strip-major bucketed pipeline (XCD-local L2 gathers) ----
        float*    dis  = (float*)ws;                       // 0 .. 400K (pad 512K)
        int*      cur  = (int*)(ws + (1u << 19));          // 512K (1563 ints)
        unsigned* ovfn = (unsigned*)(ws + 589824u);        // 576K (4B)
        uint2*    ovf  = (uint2*)(ws + 593920u);           // 580K .. +32KB
        int*      offn = (int*)(ws + 655360u);             // 640K .. 1040K (N ints)
        unsigned* recs = (unsigned*)(ws + 1572864u);       // 1.5M .. 11.1M (NBKT*CAP_B*4)
        __half*   hwa  = (__half*)(ws + 11534336u);        // 11M .. 23.8M (4 strips)
        __half*   hvb  = (__half*)(ws + 24641536u);        // 23.5M .. 36.3M (4 strips)

        zero_kernel<<<(NBKT + 256) / 256, 256, 0, stream>>>(cur, ovfn);
        partition_hier<<<PBLK, 1024, 0, stream>>>(ei, cur, recs, ovfn, ovf, E);
        sort_bucket<<<NBKT, 256, 0, stream>>>(cur, recs, ovfn, ovf, dis, offn, N);

        // layer 1 GEMM: hw1(fp16, *dis) -> hwa strips
        gemm_mfma<128><<<gemmGrid, 256, 0, stream>>>(x, W1, dis, hwa, N);
        // agg1: h(fp16) -> hvb strips
        agg_strip<true><<<NBKT * 8, 128, 0, stream>>>(cur, recs, offn, hwa, dis, b1, hvb,
                                                      ovfn, ovf, N);
        // layer 2 GEMM: hwa2 = (h @ W2)*dis -> hwa strips
        gemm_mfma_h<<<gemmGrid, 256, 0, stream>>>(hvb, W2, dis, hwa, N);
        // agg2: out(fp32) final
        agg_strip<false><<<NBKT * 8, 128, 0, stream>>>(cur, recs, offn, hwa, dis, b2, out,
                                                       ovfn, ovf, N);
    } else {
        // ---- fallback: atomic path (fp32 throughout) ----
        float* dis  = (float*)ws;
        float* bufA = (float*)(ws + (1 << 19));
        const size_t featBytes = (size_t)N * 64 * sizeof(float);

        fill_kernel<<<(N + 255) / 256, 256, 0, stream>>>(dis, 1.0f, N);
        degree_kernel<<<2048, 256, 0, stream>>>(ei, dis, E);
        rsqrt_kernel<<<(N + 255) / 256, 256, 0, stream>>>(dis, N);

        gemm_tile<128><<<gemmGrid, 256, 0, stream>>>(x, W1, bufA, N);
        hipMemsetAsync(out, 0, featBytes, stream);
        scatter_kernel<<<2048, 256, 0, stream>>>(ei, bufA, dis, out, E);
        finalize_kernel<<<(N * 64 + 255) / 256, 256, 0, stream>>>(out, bufA, dis, b1, N);

        gemm_tile<64><<<gemmGrid, 256, 0, stream>>>(out, W2, bufA, N);
        hipMemsetAsync(out, 0, featBytes, stream);
        scatter_kernel<<<2048, 256, 0, stream>>>(ei, bufA, dis, out, E);
        finalize_kernel<<<(N * 64 + 255) / 256, 256, 0, stream>>>(out, bufA, dis, b2, N);
    }
}

// Round 16
// 118.251 us; speedup vs baseline: 1.2540x; 1.2540x over previous
//
#include <hip/hip_runtime.h>
#include <hip/hip_fp16.h>
#include <cstdint>
#include <cstddef>

#define NN 100000
#define NE 1200000
#define NBKT 1563              // (NN+63)/64 buckets of 64 dst nodes
#define CAP_B 1536             // slab capacity per bucket (mean 768, +27 sigma)
#define PBLK 256               // partition blocks (1 per CU)
#define PCHK ((NE + PBLK - 1) / PBLK)   // 4688 edges per partition block

typedef _Float16 f16x8 __attribute__((ext_vector_type(8)));
typedef float f32x4 __attribute__((ext_vector_type(4)));

// ================= init: zero cursors + overflow count in ONE dispatch =================
__global__ void zero_kernel(int* __restrict__ cur, unsigned* __restrict__ ovfn) {
    int i = blockIdx.x * blockDim.x + threadIdx.x;
    if (i < NBKT) cur[i] = 0;
    if (i == NBKT) *ovfn = 0;
}

// ============ partition: hierarchical reservation; 1024 thr = 4 waves/SIMD TLP ============
__global__ __launch_bounds__(1024) void partition_hier(
    const int* __restrict__ ei, int* __restrict__ cur,
    unsigned* __restrict__ recs, unsigned* __restrict__ ovfn,
    uint2* __restrict__ ovf, int E) {
    __shared__ int hist[NBKT];
    __shared__ int base[NBKT];
    const int tid = threadIdx.x;
    for (int i = tid; i < NBKT; i += 1024) hist[i] = 0;
    __syncthreads();
    const int lo = blockIdx.x * PCHK, hi = min(lo + PCHK, E);
    for (int e = lo + tid; e < hi; e += 1024)
        atomicAdd(&hist[ei[E + e] >> 6], 1);
    __syncthreads();
    for (int i = tid; i < NBKT; i += 1024) {
        int c = hist[i];
        base[i] = c ? atomicAdd(&cur[i], c) : 0;
        hist[i] = 0;   // reuse as local cursor
    }
    __syncthreads();
    for (int e = lo + tid; e < hi; e += 1024) {
        int d = ei[E + e];
        int s = ei[e];
        int b = d >> 6;
        int lp = atomicAdd(&hist[b], 1);
        int pos = base[b] + lp;
        if (pos < CAP_B)
            recs[(size_t)b * CAP_B + pos] = ((unsigned)s << 6) | (unsigned)(d & 63);
        else {   // ~27 sigma out; keep exact anyway
            unsigned o = atomicAdd(ovfn, 1);
            if (o < 4096) ovf[o] = make_uint2((unsigned)s, (unsigned)d);
        }
    }
}

// ============ one-time per-bucket counting sort + per-node offsets + dis ============
__global__ __launch_bounds__(256) void sort_bucket(
    const int* __restrict__ cur, unsigned* __restrict__ recs,
    const unsigned* __restrict__ ovfn, const uint2* __restrict__ ovf,
    float* __restrict__ dis, int* __restrict__ offn, int n) {
    __shared__ unsigned raw[CAP_B], srt[CAP_B];
    __shared__ int cnt[64], pfx[64], woff[64];
    const int b = blockIdx.x, tid = threadIdx.x;
    if (tid < 64) cnt[tid] = 0;
    const int c = min(cur[b], CAP_B);
    unsigned* slab = recs + (size_t)b * CAP_B;
    for (int i = tid; i < c; i += 256) raw[i] = slab[i];
    __syncthreads();
    for (int i = tid; i < c; i += 256) atomicAdd(&cnt[raw[i] & 63], 1);
    __syncthreads();
    if (tid < 64) pfx[tid] = cnt[tid];
    __syncthreads();
    for (int s = 1; s < 64; s <<= 1) {
        int v = (tid < 64 && tid >= s) ? pfx[tid - s] : 0;
        __syncthreads();
        if (tid < 64) pfx[tid] += v;
        __syncthreads();
    }
    if (tid < 64) woff[tid] = pfx[tid] - cnt[tid];
    __syncthreads();
    for (int i = tid; i < c; i += 256) {
        unsigned k = raw[i];
        int p = atomicAdd(&woff[k & 63], 1);
        srt[p] = k >> 6;          // plain src id, sorted by dst-low
    }
    __syncthreads();
    for (int i = tid; i < c; i += 256) slab[i] = srt[i];
    if (tid < 64) {
        int g = b * 64 + tid;
        if (g < n) {
            int cc = cnt[tid];
            unsigned no = *ovfn;
            for (unsigned i = 0; i < no; i++)
                if ((int)ovf[i].y == g) cc++;
            dis[g] = rsqrtf((float)cc + 1.0f);   // +1 self-loop
            offn[g] = pfx[tid] - cnt[tid];
        }
    }
}

#define LD1(q) { float2 g01 = __half22float2(*(__half2*)&(q).x); \
                 float2 g23 = __half22float2(*(__half2*)&(q).y); \
                 a0 += g01.x; a1 += g01.y; a2 += g23.x; a3 += g23.y; }

// ============ bucket aggregation: stream sorted runs, 8-deep register gather ============
// hwa rows already carry dis[src]; output applies dis[dst], bias, relu.
template <bool HALF_OUT>
__global__ __launch_bounds__(256) void agg_bucket4(
    const int* __restrict__ cur, const unsigned* __restrict__ recs,
    const int* __restrict__ offn, const __half* __restrict__ hw,
    const float* __restrict__ dis, const float* __restrict__ bias,
    void* __restrict__ outv,
    const unsigned* __restrict__ ovfn, const uint2* __restrict__ ovf, int n) {
    __shared__ unsigned srec[CAP_B];
    __shared__ int soff[65];
    __shared__ float disD[64];
    const int b = blockIdx.x, tid = threadIdx.x;
    const int c = min(cur[b], CAP_B);
    const unsigned* slab = recs + (size_t)b * CAP_B;
    for (int i = tid; i < c; i += 256) srec[i] = slab[i];
    if (tid < 64) {
        int g = b * 64 + tid;
        disD[tid] = (g < n) ? dis[g] : 0.f;
        soff[tid] = (g < n) ? offn[g] : c;
    }
    if (tid == 0) soff[64] = c;
    __syncthreads();

    const uint2* hwq = (const uint2*)hw;   // row = 16 uint2 (64 fp16)
    const int slot = tid >> 4, sub = tid & 15;
    const unsigned no = *ovfn;
    const float4 bb = ((const float4*)bias)[sub];

    for (int j = 0; j < 4; j++) {
        int nl = slot * 4 + j;
        int g = b * 64 + nl;
        if (g >= n) break;
        uint2 qs = hwq[(size_t)g * 16 + sub];   // self row (carries dis[g])
        float a0 = 0.f, a1 = 0.f, a2 = 0.f, a3 = 0.f;
        LD1(qs);

        int e = soff[nl], end = soff[nl + 1];
        for (; e + 8 <= end; e += 8) {
            uint2 q0 = hwq[(size_t)srec[e + 0] * 16 + sub];
            uint2 q1 = hwq[(size_t)srec[e + 1] * 16 + sub];
            uint2 q2 = hwq[(size_t)srec[e + 2] * 16 + sub];
            uint2 q3 = hwq[(size_t)srec[e + 3] * 16 + sub];
            uint2 q4 = hwq[(size_t)srec[e + 4] * 16 + sub];
            uint2 q5 = hwq[(size_t)srec[e + 5] * 16 + sub];
            uint2 q6 = hwq[(size_t)srec[e + 6] * 16 + sub];
            uint2 q7 = hwq[(size_t)srec[e + 7] * 16 + sub];
            LD1(q0); LD1(q1); LD1(q2); LD1(q3);
            LD1(q4); LD1(q5); LD1(q6); LD1(q7);
        }
        for (; e + 4 <= end; e += 4) {
            uint2 q0 = hwq[(size_t)srec[e + 0] * 16 + sub];
            uint2 q1 = hwq[(size_t)srec[e + 1] * 16 + sub];
            uint2 q2 = hwq[(size_t)srec[e + 2] * 16 + sub];
            uint2 q3 = hwq[(size_t)srec[e + 3] * 16 + sub];
            LD1(q0); LD1(q1); LD1(q2); LD1(q3);
        }
        for (; e < end; e++) {
            uint2 q = hwq[(size_t)srec[e] * 16 + sub];
            LD1(q);
        }
        for (unsigned i = 0; i < no; i++) {
            uint2 o = ovf[i];
            if ((int)o.y == g) { uint2 q = hwq[(size_t)o.x * 16 + sub]; LD1(q); }
        }
        float di = disD[nl];
        float o0 = fmaf(di, a0, bb.x);
        float o1 = fmaf(di, a1, bb.y);
        float o2 = fmaf(di, a2, bb.z);
        float o3 = fmaf(di, a3, bb.w);
        o0 = o0 > 0.f ? o0 : 0.f;
        o1 = o1 > 0.f ? o1 : 0.f;
        o2 = o2 > 0.f ? o2 : 0.f;
        o3 = o3 > 0.f ? o3 : 0.f;
        if (HALF_OUT) {
            __half2 p01 = __floats2half2_rn(o0, o1);
            __half2 p23 = __floats2half2_rn(o2, o3);
            uint2 pk;
            pk.x = *(unsigned*)&p01;
            pk.y = *(unsigned*)&p23;
            ((uint2*)outv)[(size_t)g * 16 + sub] = pk;
        } else {
            float4 oo; oo.x = o0; oo.y = o1; oo.z = o2; oo.w = o3;
            ((float4*)outv)[(size_t)g * 16 + sub] = oo;
        }
    }
}

// ============ MFMA GEMM (fp32 in): C = (A @ W) * dis[row], fp16 out ============
template <int K>
__global__ __launch_bounds__(256) void gemm_mfma(const float* __restrict__ A,
                                                 const float* __restrict__ W,
                                                 const float* __restrict__ dis,
                                                 __half* __restrict__ C, int n) {
    constexpr int KB = K / 32;
    __shared__ f16x8 sAf[4 * KB * 64];   // [rt][kb][lane]
    __shared__ f16x8 sWf[4 * KB * 64];   // [ct][kb][lane]
    __shared__ float sdis[64];
    const int tid = threadIdx.x;
    const int row0 = blockIdx.x * 64;

    if (tid < 64) {
        int rw = row0 + tid;
        sdis[tid] = (rw < n) ? dis[rw] : 0.f;
    }

    _Float16* sAh = (_Float16*)sAf;
    const float4* A4 = (const float4*)A;
#pragma unroll
    for (int it = 0; it < K / 16; ++it) {
        int f = it * 256 + tid;
        int row = f / (K / 4);
        int kq = f % (K / 4);
        int k0 = kq * 4;
        float4 a;
        if (row0 + row < n) a = A4[(size_t)(row0 + row) * (K / 4) + kq];
        else { a.x = 0.f; a.y = 0.f; a.z = 0.f; a.w = 0.f; }
        int rt = row >> 4;
        int kb = k0 >> 5;
        int lane = (row & 15) | (((k0 >> 3) & 3) << 4);
        int base = ((rt * KB + kb) * 64 + lane) * 8 + (k0 & 7);
        sAh[base + 0] = (_Float16)a.x;
        sAh[base + 1] = (_Float16)a.y;
        sAh[base + 2] = (_Float16)a.z;
        sAh[base + 3] = (_Float16)a.w;
    }
    _Float16* sWh = (_Float16*)sWf;
    {
        int nn = tid & 63;
        int ct = nn >> 4;
        int lbase = nn & 15;
        for (int k = tid >> 6; k < K; k += 4) {
            float w = W[(size_t)k * 64 + nn];
            int kb = k >> 5;
            int lane = lbase | (((k >> 3) & 3) << 4);
            sWh[((ct * KB + kb) * 64 + lane) * 8 + (k & 7)] = (_Float16)w;
        }
    }
    __syncthreads();

    const int wv = tid >> 6;
    const int lane = tid & 63;
    f32x4 acc[4];
#pragma unroll
    for (int rt = 0; rt < 4; ++rt) acc[rt] = (f32x4){0.f, 0.f, 0.f, 0.f};

#pragma unroll
    for (int kb = 0; kb < KB; ++kb) {
        f16x8 bf = sWf[(wv * KB + kb) * 64 + lane];
#pragma unroll
        for (int rt = 0; rt < 4; ++rt) {
            f16x8 af = sAf[(rt * KB + kb) * 64 + lane];
            acc[rt] = __builtin_amdgcn_mfma_f32_16x16x32_f16(af, bf, acc[rt], 0, 0, 0);
        }
    }

    int col = wv * 16 + (lane & 15);
    int rbase = (lane >> 4) * 4;
#pragma unroll
    for (int rt = 0; rt < 4; ++rt) {
#pragma unroll
        for (int r = 0; r < 4; ++r) {
            int row = row0 + rt * 16 + rbase + r;
            if (row < n)
                C[(size_t)row * 64 + col] = __float2half(acc[rt][r] * sdis[rt * 16 + rbase + r]);
        }
    }
}

// ============ MFMA GEMM (fp16 in, K=64): C = (A @ W) * dis[row], fp16 out ============
__global__ __launch_bounds__(256) void gemm_mfma_h(const __half* __restrict__ A,
                                                   const float* __restrict__ W,
                                                   const float* __restrict__ dis,
                                                   __half* __restrict__ C, int n) {
    constexpr int K = 64, KB = 2;
    __shared__ f16x8 sAf[4 * KB * 64];
    __shared__ f16x8 sWf[4 * KB * 64];
    __shared__ float sdis[64];
    const int tid = threadIdx.x;
    const int row0 = blockIdx.x * 64;

    if (tid < 64) {
        int rw = row0 + tid;
        sdis[tid] = (rw < n) ? dis[rw] : 0.f;
    }

    _Float16* sAh = (_Float16*)sAf;
    const uint2* A2 = (const uint2*)A;   // 4 fp16 per uint2, 16 per row
#pragma unroll
    for (int it = 0; it < 4; ++it) {     // 64 rows * 16 = 1024 uint2 / 256 thr
        int f = it * 256 + tid;
        int row = f >> 4;
        int kq = f & 15;
        int k0 = kq * 4;
        uint2 a;
        if (row0 + row < n) a = A2[(size_t)(row0 + row) * 16 + kq];
        else { a.x = 0u; a.y = 0u; }
        _Float16* ap = (_Float16*)&a;
        int rt = row >> 4;
        int kb = k0 >> 5;
        int lane = (row & 15) | (((k0 >> 3) & 3) << 4);
        int base = ((rt * KB + kb) * 64 + lane) * 8 + (k0 & 7);
        sAh[base + 0] = ap[0];
        sAh[base + 1] = ap[1];
        sAh[base + 2] = ap[2];
        sAh[base + 3] = ap[3];
    }
    _Float16* sWh = (_Float16*)sWf;
    {
        int nn = tid & 63;
        int ct = nn >> 4;
        int lbase = nn & 15;
        for (int k = tid >> 6; k < K; k += 4) {
            float w = W[(size_t)k * 64 + nn];
            int kb = k >> 5;
            int lane = lbase | (((k >> 3) & 3) << 4);
            sWh[((ct * 2 + kb) * 64 + lane) * 8 + (k & 7)] = (_Float16)w;
        }
    }
    __syncthreads();

    const int wv = tid >> 6;
    const int lane = tid & 63;
    f32x4 acc[4];
#pragma unroll
    for (int rt = 0; rt < 4; ++rt) acc[rt] = (f32x4){0.f, 0.f, 0.f, 0.f};

#pragma unroll
    for (int kb = 0; kb < KB; ++kb) {
        f16x8 bf = sWf[(wv * KB + kb) * 64 + lane];
#pragma unroll
        for (int rt = 0; rt < 4; ++rt) {
            f16x8 af = sAf[(rt * KB + kb) * 64 + lane];
            acc[rt] = __builtin_amdgcn_mfma_f32_16x16x32_f16(af, bf, acc[rt], 0, 0, 0);
        }
    }

    int col = wv * 16 + (lane & 15);
    int rbase = (lane >> 4) * 4;
#pragma unroll
    for (int rt = 0; rt < 4; ++rt) {
#pragma unroll
        for (int r = 0; r < 4; ++r) {
            int row = row0 + rt * 16 + rbase + r;
            if (row < n)
                C[(size_t)row * 64 + col] = __float2half(acc[rt][r] * sdis[rt * 16 + rbase + r]);
        }
    }
}

// ================= fallback (atomic path, small ws) =================
__global__ void fill_kernel(float* __restrict__ p, float v, int n) {
    int i = blockIdx.x * blockDim.x + threadIdx.x;
    if (i < n) p[i] = v;
}
__global__ void degree_kernel(const int* __restrict__ ei, float* __restrict__ deg, int E) {
    int stride = gridDim.x * blockDim.x;
    for (int e = blockIdx.x * blockDim.x + threadIdx.x; e < E; e += stride)
        atomicAdd(&deg[ei[E + e]], 1.0f);
}
__global__ void rsqrt_kernel(float* __restrict__ deg, int n) {
    int i = blockIdx.x * blockDim.x + threadIdx.x;
    if (i < n) deg[i] = rsqrtf(deg[i]);
}
template <int K>
__global__ __launch_bounds__(256) void gemm_tile(const float* __restrict__ A,
                                                 const float* __restrict__ W,
                                                 float* __restrict__ C, int n) {
    __shared__ float sA[64 * K];
    __shared__ float sW[K * 64];
    const int tid = threadIdx.x;
    const int row0 = blockIdx.x * 64;
    const int rows = min(64, n - row0);
    const float4* W4 = (const float4*)W;
    float4* sW4 = (float4*)sW;
    for (int i = tid; i < K * 16; i += 256) sW4[i] = W4[i];
    const float4* A4 = (const float4*)(A + (size_t)row0 * K);
    float4* sA4 = (float4*)sA;
    const int nElem = rows * (K / 4);
    for (int i = tid; i < nElem; i += 256) sA4[i] = A4[i];
    __syncthreads();
    const int col = tid & 63;
    const int ty  = tid >> 6;
    float acc[16];
#pragma unroll
    for (int r = 0; r < 16; r++) acc[r] = 0.f;
    for (int k = 0; k < K; k += 4) {
        float w0 = sW[(k + 0) * 64 + col];
        float w1 = sW[(k + 1) * 64 + col];
        float w2 = sW[(k + 2) * 64 + col];
        float w3 = sW[(k + 3) * 64 + col];
#pragma unroll
        for (int r = 0; r < 16; r++) {
            const float4 a = *(const float4*)&sA[(ty + 4 * r) * K + k];
            acc[r] = fmaf(a.x, w0, acc[r]);
            acc[r] = fmaf(a.y, w1, acc[r]);
            acc[r] = fmaf(a.z, w2, acc[r]);
            acc[r] = fmaf(a.w, w3, acc[r]);
        }
    }
#pragma unroll
    for (int r = 0; r < 16; r++) {
        int row = ty + 4 * r;
        if (row < rows) C[(size_t)(row0 + row) * 64 + col] = acc[r];
    }
}
__global__ void scatter_kernel(const int* __restrict__ ei, const float* __restrict__ hw,
                               const float* __restrict__ dis, float* __restrict__ agg, int E) {
    int gtid = blockIdx.x * blockDim.x + threadIdx.x;
    int wave = gtid >> 6, lane = threadIdx.x & 63;
    int nwaves = (gridDim.x * blockDim.x) >> 6;
    for (int e = wave; e < E; e += nwaves) {
        int s = ei[e], d = ei[E + e];
        float v = hw[(size_t)s * 64 + lane] * dis[s] * dis[d];
        atomicAdd(&agg[(size_t)d * 64 + lane], v);
    }
}
__global__ void finalize_kernel(float* __restrict__ agg, const float* __restrict__ hw,
                                const float* __restrict__ dis, const float* __restrict__ b, int n) {
    int i = blockIdx.x * blockDim.x + threadIdx.x;
    if (i < n * 64) {
        int node = i >> 6, col = i & 63;
        float di = dis[node];
        float v = agg[i] + hw[i] * di * di + b[col];
        agg[i] = v > 0.0f ? v : 0.0f;
    }
}

extern "C" void kernel_launch(void* const* d_in, const int* in_sizes, int n_in,
                              void* d_out, int out_size, void* d_ws, size_t ws_size,
                              hipStream_t stream) {
    const float* x  = (const float*)d_in[0];
    const int*   ei = (const int*)d_in[1];   // int32 [2, E] flat
    const float* W1 = (const float*)d_in[2];
    const float* b1 = (const float*)d_in[3];
    const float* W2 = (const float*)d_in[4];
    const float* b2 = (const float*)d_in[5];
    float* out = (float*)d_out;

    const int N = NN, E = NE;
    char* ws = (char*)d_ws;
    const int gemmGrid = (N + 63) / 64;

    if (ws_size >= 38200000u) {
        // ---- factorized-norm bucketed pipeline (sort-once, fp16 inter-layer) ----
        float*    dis  = (float*)ws;                       // 0 .. 400K (pad 512K)
        int*      cur  = (int*)(ws + (1u << 19));          // 512K (1563 ints)
        unsigned* ovfn = (unsigned*)(ws + 589824u);        // 576K (4B)
        uint2*    ovf  = (uint2*)(ws + 593920u);           // 580K .. +32KB
        int*      offn = (int*)(ws + 655360u);             // 640K .. 1040K (N ints)
        unsigned* recs = (unsigned*)(ws + 1572864u);       // 1.5M .. 10.7M (NBKT*CAP_B*4)
        __half*   hwa  = (__half*)(ws + 11534336u);        // 11M .. 23.8M (fp16)
        __half*   hvb  = (__half*)(ws + 25165824u);        // 24M .. 36.8M (fp16 h)

        zero_kernel<<<(NBKT + 256) / 256, 256, 0, stream>>>(cur, ovfn);
        partition_hier<<<PBLK, 1024, 0, stream>>>(ei, cur, recs, ovfn, ovf, E);
        sort_bucket<<<NBKT, 256, 0, stream>>>(cur, recs, ovfn, ovf, dis, offn, N);

        // layer 1: hw1(fp16, *dis) -> hwa; h(fp16) -> hvb
        gemm_mfma<128><<<gemmGrid, 256, 0, stream>>>(x, W1, dis, hwa, N);
        agg_bucket4<true><<<NBKT, 256, 0, stream>>>(cur, recs, offn, hwa, dis, b1, hvb, ovfn, ovf, N);
        // layer 2: hw2(fp16, *dis) -> hwa; out(fp32) final
        gemm_mfma_h<<<gemmGrid, 256, 0, stream>>>(hvb, W2, dis, hwa, N);
        agg_bucket4<false><<<NBKT, 256, 0, stream>>>(cur, recs, offn, hwa, dis, b2, out, ovfn, ovf, N);
    } else {
        // ---- fallback: atomic path (fp32 throughout) ----
        float* dis  = (float*)ws;
        float* bufA = (float*)(ws + (1 << 19));
        const size_t featBytes = (size_t)N * 64 * sizeof(float);

        fill_kernel<<<(N + 255) / 256, 256, 0, stream>>>(dis, 1.0f, N);
        degree_kernel<<<2048, 256, 0, stream>>>(ei, dis, E);
        rsqrt_kernel<<<(N + 255) / 256, 256, 0, stream>>>(dis, N);

        gemm_tile<128><<<gemmGrid, 256, 0, stream>>>(x, W1, bufA, N);
        hipMemsetAsync(out, 0, featBytes, stream);
        scatter_kernel<<<2048, 256, 0, stream>>>(ei, bufA, dis, out, E);
        finalize_kernel<<<(N * 64 + 255) / 256, 256, 0, stream>>>(out, bufA, dis, b1, N);

        gemm_tile<64><<<gemmGrid, 256, 0, stream>>>(out, W2, bufA, N);
        hipMemsetAsync(out, 0, featBytes, stream);
        scatter_kernel<<<2048, 256, 0, stream>>>(ei, bufA, dis, out, E);
        finalize_kernel<<<(N * 64 + 255) / 256, 256, 0, stream>>>(out, bufA, dis, b2, N);
    }
}